// Round 10
// baseline (402.449 us; speedup 1.0000x reference)
//
#include <hip/hip_runtime.h>
#include <hip/hip_bf16.h>
#include <cstddef>

// MultiHeadAttention: B=2, S=2048, E=1024, H=16, D=64. I/O fp32, compute bf16.
// SINGLE plain-launch kernel with a SOFTWARE grid barrier (device-scope
// atomics + __threadfence release/acquire). r8/r9 forensics: cooperative
// launch silently never ran in this harness (output == memset zeros, error
// == max|ref| = 9.13e-2, identical across fence variants). Plain launch +
// capacity-guaranteed co-residency (512 blocks = exactly 2/CU by LDS+VGPR)
// replaces it. Host falls back to the proven 5-kernel r7 path if ws_size
// lacks the 64 barrier bytes.
#define SEQ   2048
#define EMB   1024
#define NHEAD 16
#define HDIM  64
#define BATCH 2
#define MROWS (BATCH * SEQ)   // 4096
#define BH_STRIDE (SEQ * HDIM)
#define CSC_F 0.180336874f    // 0.125 * log2(e), folded into Wq/bq

typedef __attribute__((ext_vector_type(8))) short frag_ab;   // 8 bf16 = 4 VGPR
typedef __attribute__((ext_vector_type(4))) float frag_cd;   // 4 fp32 acc

#define GLOBAL_AS __attribute__((address_space(1)))
#define LDS_AS    __attribute__((address_space(3)))

__device__ __forceinline__ unsigned short f2bf(float f) {      // RNE
    unsigned u = __float_as_uint(f);
    u += 0x7FFF + ((u >> 16) & 1);
    return (unsigned short)(u >> 16);
}
__device__ __forceinline__ unsigned short f2bf_trunc(float f) { // truncate (P only)
    return (unsigned short)(__float_as_uint(f) >> 16);
}
__device__ __forceinline__ void gld16(const unsigned short* g, unsigned short* l) {
    __builtin_amdgcn_global_load_lds((GLOBAL_AS const unsigned int*)g,
                                     (LDS_AS unsigned int*)l, 16, 0, 0);
}
__device__ __forceinline__ void cvt8(const float* __restrict__ s,
                                     unsigned short* __restrict__ d, float sc) {
    float4 f0 = *(const float4*)s;
    float4 f1 = *(const float4*)(s + 4);
    ushort4 lo, hi;
    lo.x = f2bf(f0.x * sc); lo.y = f2bf(f0.y * sc); lo.z = f2bf(f0.z * sc); lo.w = f2bf(f0.w * sc);
    hi.x = f2bf(f1.x * sc); hi.y = f2bf(f1.y * sc); hi.z = f2bf(f1.z * sc); hi.w = f2bf(f1.w * sc);
    *(ushort4*)d = lo;
    *(ushort4*)(d + 4) = hi;
}

// ---------------------------------------------------------------------------
// Software grid barrier. All 512 blocks are co-resident by construction
// (LDS 41.5 KB -> 3 blocks/CU; launch_bounds(256,2) -> 2 blocks/CU; grid =
// 2 x 256 CUs exactly). Counters are per-barrier (no reuse within a launch)
// and re-zeroed by a graph-captured hipMemsetAsync before every launch.
// Release: __syncthreads drains the block's stores, tid0's __threadfence
// emits buffer_wbl2 (whole-L2 writeback). Acquire: tid0's post-spin
// __threadfence emits buffer_inv, then __syncthreads releases the block.
// Bounded spin: a failed assumption degrades to wrong-answer, never a hang.
// ---------------------------------------------------------------------------
__device__ __forceinline__ void grid_barrier(unsigned* __restrict__ cnt,
                                             unsigned target) {
    __syncthreads();
    if (threadIdx.x == 0) {
        __threadfence();                     // release: wb L2 to coherent point
        atomicAdd(cnt, 1u);
        unsigned iters = 0;
        while (atomicAdd(cnt, 0u) < target) {  // RMW: always coherent
            __builtin_amdgcn_s_sleep(8);
            if (++iters > 100000000u) break;   // failsafe, ~several seconds
        }
        __threadfence();                     // acquire: inv L1/L2
    }
    __syncthreads();
}

// ---------------------------------------------------------------------------
// 128xBNx64 GEMM tile body, XOR-SWIZZLED LDS (r7-proven, parameterized by lb).
// QKV=true: LDS-assembled fragment-layout epilogue; QKV=false: fp32 row-major.
// ---------------------------------------------------------------------------
template <bool QKV, int BN>
__device__ __forceinline__ void gemm_body(int lb, unsigned short* __restrict__ SB,
                                          const unsigned short* __restrict__ A,
                                          const unsigned short* __restrict__ W0,
                                          const unsigned short* __restrict__ W1,
                                          const unsigned short* __restrict__ W2,
                                          const float* __restrict__ b0,
                                          const float* __restrict__ b1,
                                          const float* __restrict__ b2,
                                          void* __restrict__ o0,
                                          void* __restrict__ o1,
                                          void* __restrict__ o2) {
    constexpr int K = EMB;
    constexpr int NTC = BN / 32;             // n-fragments per wave (4 or 2)
    unsigned short* As = SB;
    unsigned short* Bs = SB + 8192;

    const int g8 = lb & 7, t = lb >> 3;
    const int my = g8 * 4 + (t & 3);
    const int mx = QKV ? ((t >> 2) & 7) : (t >> 2);
    const int z = QKV ? (t >> 5) : 0;

    const unsigned short* W = (z == 0) ? W0 : (z == 1) ? W1 : W2;
    const float* bias = (z == 0) ? b0 : (z == 1) ? b1 : b2;
    void* outv = (z == 0) ? o0 : (z == 1) ? o1 : o2;

    const int m0 = my * 128;
    const int n0 = mx * BN;
    const int tid = threadIdx.x;
    const int lane = tid & 63, w = tid >> 6;
    const int wr = w >> 1, wc = w & 1;
    const int lm = lane & 15, lq = lane >> 4;

    const int cs = (((tid & 7) ^ ((tid >> 3) & 7)) << 3);
    const int sx = lm & 7;   // fragment-row swizzle key (row&7 == lm&7)

    frag_cd acc[4][NTC];
#pragma unroll
    for (int mt = 0; mt < 4; ++mt)
#pragma unroll
        for (int nt = 0; nt < NTC; ++nt) acc[mt][nt] = (frag_cd){0.f, 0.f, 0.f, 0.f};

    for (int k0 = 0; k0 < K; k0 += 64) {
#pragma unroll
        for (int it = 0; it < 4; ++it) {
            int flat = (it * 256 + tid) * 8;
            int r = flat >> 6;
            gld16(&A[(size_t)(m0 + r) * K + k0 + cs], &As[flat]);
        }
#pragma unroll
        for (int it = 0; it < BN / 32; ++it) {
            int flat = (it * 256 + tid) * 8;
            int r = flat >> 6;
            gld16(&W[(size_t)(n0 + r) * K + k0 + cs], &Bs[flat]);
        }
        __syncthreads();

#pragma unroll
        for (int kk = 0; kk < 2; ++kk) {
            frag_ab af[4], bf[NTC];
#pragma unroll
            for (int mt = 0; mt < 4; ++mt)
                af[mt] = *(const frag_ab*)&As[(wr * 64 + mt * 16 + lm) * 64
                                              + (((kk * 4 + lq) ^ sx) << 3)];
#pragma unroll
            for (int nt = 0; nt < NTC; ++nt)
                bf[nt] = *(const frag_ab*)&Bs[(wc * (BN / 2) + nt * 16 + lm) * 64
                                              + (((kk * 4 + lq) ^ sx) << 3)];
#pragma unroll
            for (int mt = 0; mt < 4; ++mt)
#pragma unroll
                for (int nt = 0; nt < NTC; ++nt)
                    acc[mt][nt] = __builtin_amdgcn_mfma_f32_16x16x32_bf16(
                        af[mt], bf[nt], acc[mt][nt], 0, 0, 0);
        }
        __syncthreads();
    }

    if constexpr (!QKV) {
#pragma unroll
        for (int mt = 0; mt < 4; ++mt)
#pragma unroll
            for (int nt = 0; nt < NTC; ++nt) {
                int col = n0 + wc * (BN / 2) + nt * 16 + lm;
                float bv = bias[col];
#pragma unroll
                for (int r = 0; r < 4; ++r) {
                    int row = m0 + wr * 64 + mt * 16 + lq * 4 + r;
                    ((float*)outv)[(size_t)row * EMB + col] = acc[mt][nt][r] + bv;
                }
            }
    } else {
        const float bscale = (z == 0) ? CSC_F : 1.0f;
#pragma unroll
        for (int mt = 0; mt < 4; ++mt)
#pragma unroll
            for (int nt = 0; nt < NTC; ++nt) {
                int col = n0 + wc * 64 + nt * 16 + lm;
                float bv = bias[col] * bscale;
#pragma unroll
                for (int r = 0; r < 4; ++r) {
                    unsigned short o = f2bf(acc[mt][nt][r] + bv);
                    int l, pos;
                    if (z < 2) {   // Q/K frag layout
                        l = wc * 16 + (wr * 4 + mt) * 2 + (nt >> 1);
                        pos = ((nt * 2 + (lm >> 3)) & 3) * 128 + (lq * 4 + r) * 8 + (lm & 7);
                    } else {       // V^T frag layout
                        l = wc * 16 + (wr * 2 + (mt >> 1)) * 4 + nt;
                        pos = ((mt & 1) * 2 + (lq >> 1)) * 128 + lm * 8 + (lq & 1) * 4 + r;
                    }
                    SB[l * 512 + pos] = o;
                }
            }
        __syncthreads();

        unsigned short* out = (unsigned short*)outv;
        const int b = m0 >> 11;
        const int hb = n0 >> 6;
        const int sg16 = (m0 & (SEQ - 1)) >> 4;
        const int sb32 = (m0 & (SEQ - 1)) >> 5;
#pragma unroll
        for (int it = 0; it < 8; ++it) {
            int cl = it * 4 + w;
            uint4 v = *(const uint4*)&SB[cl * 512 + lane * 8];
            size_t chunk;
            if (z < 2) {
                int h = cl >> 4, sg = (cl >> 1) & 7, dh = cl & 1;
                chunk = ((size_t)(b * NHEAD + hb + h) * 128 + sg16 + sg) * 2 + dh;
            } else {
                int h = cl >> 4, sb = (cl >> 2) & 3, dq = cl & 3;
                chunk = ((size_t)(b * NHEAD + hb + h) * 64 + sb32 + sb) * 4 + dq;
            }
            *(uint4*)&out[chunk * 512 + lane * 8] = v;
        }
    }
    __syncthreads();   // safe reuse of SB by the caller's next tile/phase
}

// ---------------------------------------------------------------------------
// Flash attention body (round-3/7 verbatim, best measured 46.1-46.8 us).
// ---------------------------------------------------------------------------
#define PSTRIDE 72
#define CSTRIDE 81   // combine-buffer float stride (odd => conflict-free)
#define SMEM_BYTES (2 * 64 * CSTRIDE * 4)   // 41472

__device__ __forceinline__ void attn_body(int bidx, unsigned char* __restrict__ SMEM,
                                          const unsigned short* __restrict__ Q,
                                          const unsigned short* __restrict__ Kf,
                                          const unsigned short* __restrict__ Vf,
                                          unsigned short* __restrict__ O) {
    const int g8 = bidx & 7, t = bidx >> 3;
    const int bh = g8 * 4 + (t & 3);
    const int qt = t >> 2;                  // 0..15
    const int w = threadIdx.x >> 6, lane = threadIdx.x & 63;
    const int lm = lane & 15, lq = lane >> 4;
    const int qs = w & 1;                   // q-slot within block (0,1)
    const int kh = w >> 1;                  // key half (0,1)

    unsigned short* P = (unsigned short*)SMEM;

    const unsigned short* Qb = Q + (size_t)bh * BH_STRIDE;
    const unsigned short* Kb = Kf + (size_t)bh * BH_STRIDE;
    const unsigned short* Vb = Vf + (size_t)bh * BH_STRIDE;

    const int ga = qt * 8 + qs * 4;         // first 16-row group of this wave
    frag_ab qf[4][2];
#pragma unroll
    for (int qi = 0; qi < 4; ++qi) {
        qf[qi][0] = *(const frag_ab*)&Qb[(((ga + qi) * 2 + 0) * 64 + lane) * 8];
        qf[qi][1] = *(const frag_ab*)&Qb[(((ga + qi) * 2 + 1) * 64 + lane) * 8];
    }

    frag_ab vone;
#pragma unroll
    for (int j = 0; j < 8; ++j) vone[j] = (short)0x3F80;   // bf16 1.0

    frag_cd oa[4][4], oc[4];
#pragma unroll
    for (int qi = 0; qi < 4; ++qi) {
        oc[qi] = (frag_cd){0.f, 0.f, 0.f, 0.f};
#pragma unroll
        for (int dt = 0; dt < 4; ++dt) oa[qi][dt] = (frag_cd){0.f, 0.f, 0.f, 0.f};
    }

    unsigned short* Pw = &P[w * (64 * PSTRIDE)];
    const frag_cd z = (frag_cd){0.f, 0.f, 0.f, 0.f};

    const int j_base = kh * (SEQ / 2);
    for (int jj = 0; jj < SEQ / 2; jj += 64) {
        const int j = j_base + jj;
        const int kg = j >> 4, jb = j >> 5;

        frag_ab kc[4][2], vc[2][4];
#pragma unroll
        for (int c = 0; c < 4; ++c) {
            kc[c][0] = *(const frag_ab*)&Kb[(((kg + c) * 2 + 0) * 64 + lane) * 8];
            kc[c][1] = *(const frag_ab*)&Kb[(((kg + c) * 2 + 1) * 64 + lane) * 8];
        }
#pragma unroll
        for (int j2 = 0; j2 < 2; ++j2)
#pragma unroll
            for (int dt = 0; dt < 4; ++dt)
                vc[j2][dt] = *(const frag_ab*)&Vb[(((jb + j2) * 4 + dt) * 64 + lane) * 8];

        // QK^T + exp2 -> P in C-layout (row = q, col = key)
#pragma unroll
        for (int c = 0; c < 4; ++c) {
#pragma unroll
            for (int qi = 0; qi < 4; ++qi) {
                frag_cd sc = __builtin_amdgcn_mfma_f32_16x16x32_bf16(qf[qi][0], kc[c][0], z, 0, 0, 0);
                sc = __builtin_amdgcn_mfma_f32_16x16x32_bf16(qf[qi][1], kc[c][1], sc, 0, 0, 0);
#pragma unroll
                for (int r = 0; r < 4; ++r) {
                    float p = __builtin_amdgcn_exp2f(sc[r]);
                    Pw[(qi * 16 + lq * 4 + r) * PSTRIDE + c * 16 + lm] = f2bf_trunc(p);
                }
            }
        }

        // C-layout -> A-layout via wave-local LDS (in-order DS, no barrier)
#pragma unroll
        for (int qi = 0; qi < 4; ++qi) {
            frag_ab pf0 = *(const frag_ab*)&Pw[(qi * 16 + lm) * PSTRIDE + lq * 8];
            frag_ab pf1 = *(const frag_ab*)&Pw[(qi * 16 + lm) * PSTRIDE + 32 + lq * 8];
            oc[qi] = __builtin_amdgcn_mfma_f32_16x16x32_bf16(pf0, vone, oc[qi], 0, 0, 0);
            oc[qi] = __builtin_amdgcn_mfma_f32_16x16x32_bf16(pf1, vone, oc[qi], 0, 0, 0);
#pragma unroll
            for (int dt = 0; dt < 4; ++dt) {
                oa[qi][dt] = __builtin_amdgcn_mfma_f32_16x16x32_bf16(pf0, vc[0][dt], oa[qi][dt], 0, 0, 0);
                oa[qi][dt] = __builtin_amdgcn_mfma_f32_16x16x32_bf16(pf1, vc[1][dt], oa[qi][dt], 0, 0, 0);
            }
        }
    }

    // ---- merge key halves: waves 2,3 dump partials; waves 0,1 reduce ----
    __syncthreads();                         // all P traffic done before alias
    float* C = (float*)SMEM;
    if (w >= 2) {
        float* dst = C + (size_t)(w - 2) * (64 * CSTRIDE) + lane * CSTRIDE;
        int idx = 0;
#pragma unroll
        for (int qi = 0; qi < 4; ++qi)
#pragma unroll
            for (int dt = 0; dt < 4; ++dt)
#pragma unroll
                for (int r = 0; r < 4; ++r) dst[idx++] = oa[qi][dt][r];
#pragma unroll
        for (int qi = 0; qi < 4; ++qi)
#pragma unroll
            for (int r = 0; r < 4; ++r) dst[idx++] = oc[qi][r];
    }
    __syncthreads();
    if (w < 2) {
        const float* src = C + (size_t)w * (64 * CSTRIDE) + lane * CSTRIDE;
        int idx = 0;
#pragma unroll
        for (int qi = 0; qi < 4; ++qi)
#pragma unroll
            for (int dt = 0; dt < 4; ++dt)
#pragma unroll
                for (int r = 0; r < 4; ++r) oa[qi][dt][r] += src[idx++];
#pragma unroll
        for (int qi = 0; qi < 4; ++qi)
#pragma unroll
            for (int r = 0; r < 4; ++r) oc[qi][r] += src[idx++];

        const int b = bh >> 4, h = bh & (NHEAD - 1);
#pragma unroll
        for (int qi = 0; qi < 4; ++qi) {
            const int q0 = (ga + qi) * 16;
#pragma unroll
            for (int r = 0; r < 4; ++r) {
                float inv = 1.0f / oc[qi][r];
                int srow = q0 + lq * 4 + r;
#pragma unroll
                for (int dt = 0; dt < 4; ++dt) {
                    int d = dt * 16 + lm;
                    O[((size_t)(b * SEQ + srow)) * EMB + h * HDIM + d] = f2bf(oa[qi][dt][r] * inv);
                }
            }
        }
    }
    __syncthreads();   // SMEM safe for next phase
}

// ---------------------------------------------------------------------------
// Fused single kernel (plain launch). 512 blocks x 256, 2 blocks/CU.
// ---------------------------------------------------------------------------
__global__ __launch_bounds__(256, 2) void mha_fused(
    const float* __restrict__ x,
    const float* __restrict__ Wq, const float* __restrict__ bq,
    const float* __restrict__ Wk, const float* __restrict__ bk,
    const float* __restrict__ Wv, const float* __restrict__ bv,
    const float* __restrict__ Wo, const float* __restrict__ bo,
    float* __restrict__ out, unsigned short* __restrict__ ws,
    unsigned* __restrict__ bar) {
    __shared__ __align__(16) unsigned char SMEM[SMEM_BYTES];

    unsigned short* xb    = ws;                       // 4096x1024 bf16
    unsigned short* q_ws  = ws + 1 * 4194304;
    unsigned short* k_ws  = ws + 2 * 4194304;
    unsigned short* vt_ws = ws + 3 * 4194304;
    unsigned short* o_ws  = xb;                       // xb dead after QKV GEMM
    unsigned short* wqkv  = (unsigned short*)out;     // out as bf16-W scratch
    unsigned short* wo_b  = q_ws;                     // q_ws dead after attn

    const int gt = blockIdx.x * 256 + threadIdx.x;    // 0..131071
    const size_t base = (size_t)gt * 8;

    // phase 1: fp32->bf16 for x (4 stripes) + Wq*csc + Wk + Wv
#pragma unroll
    for (int i = 0; i < 4; ++i)
        cvt8(x + (size_t)i * 1048576 + base, xb + (size_t)i * 1048576 + base, 1.0f);
    cvt8(Wq + base, wqkv + base, CSC_F);
    cvt8(Wk + base, wqkv + 1048576 + base, 1.0f);
    cvt8(Wv + base, wqkv + 2097152 + base, 1.0f);
    grid_barrier(bar + 0, 512);

    // phase 2: QKV projections — 768 logical tiles on 512 blocks
    for (int lb = blockIdx.x; lb < 768; lb += 512)
        gemm_body<true, 128>(lb, (unsigned short*)SMEM, xb,
                             wqkv, wqkv + 1048576, wqkv + 2097152,
                             bq, bk, bv, q_ws, k_ws, vt_ws);
    grid_barrier(bar + 1, 512);

    // phase 3: fused flash attention
    attn_body(blockIdx.x, SMEM, q_ws, k_ws, vt_ws, o_ws);
    grid_barrier(bar + 2, 512);

    // phase 4: Wo fp32->bf16 into q_ws (dead after attn)
    cvt8(Wo + base, wo_b + base, 1.0f);
    grid_barrier(bar + 3, 512);

    // phase 5: O projection (BN=64 -> 512 tiles, 1:1 with blocks)
    gemm_body<false, 64>(blockIdx.x, (unsigned short*)SMEM, o_ws,
                         wo_b, wo_b, wo_b, bo, bo, bo, out, out, out);
}

// ---------------------------------------------------------------------------
// Fallback path: the proven r7 5-kernel pipeline (183.6 us), used if ws_size
// cannot host the barrier counters.
// ---------------------------------------------------------------------------
__global__ __launch_bounds__(256) void cvt_all(const float* __restrict__ x,
                                               const float* __restrict__ Wq,
                                               const float* __restrict__ Wk,
                                               const float* __restrict__ Wv,
                                               unsigned short* __restrict__ xb,
                                               unsigned short* __restrict__ wqkv) {
    size_t e = ((size_t)blockIdx.x * 256 + threadIdx.x) * 8;
    const float* s;
    unsigned short* d;
    float sc = 1.0f;
    const size_t NX = (size_t)MROWS * EMB;
    const size_t NW = (size_t)EMB * EMB;
    if (e < NX) { s = x + e; d = xb + e; }
    else if (e < NX + NW)     { s = Wq + (e - NX);          d = wqkv + (e - NX); sc = CSC_F; }
    else if (e < NX + 2 * NW) { s = Wk + (e - NX - NW);     d = wqkv + (e - NX); }
    else                      { s = Wv + (e - NX - 2 * NW); d = wqkv + (e - NX); }
    cvt8(s, d, sc);
}

__global__ __launch_bounds__(256) void cvt_bf16(const float* __restrict__ s,
                                                unsigned short* __restrict__ d, int n) {
    int i = (blockIdx.x * 256 + threadIdx.x) * 8;
    if (i >= n) return;
    cvt8(s + i, d + i, 1.0f);
}

template <bool QKV, int BN>
__global__ __launch_bounds__(256, 3) void gemm128(const unsigned short* __restrict__ A,
                                                  const unsigned short* __restrict__ W0,
                                                  const unsigned short* __restrict__ W1,
                                                  const unsigned short* __restrict__ W2,
                                                  const float* __restrict__ b0,
                                                  const float* __restrict__ b1,
                                                  const float* __restrict__ b2,
                                                  void* __restrict__ o0,
                                                  void* __restrict__ o1,
                                                  void* __restrict__ o2) {
    __shared__ __align__(16) unsigned short SB[8192 + BN * 64];
    gemm_body<QKV, BN>(blockIdx.x, SB, A, W0, W1, W2, b0, b1, b2, o0, o1, o2);
}

__global__ __launch_bounds__(256, 2) void attn_fused(const unsigned short* __restrict__ Q,
                                                     const unsigned short* __restrict__ Kf,
                                                     const unsigned short* __restrict__ Vf,
                                                     unsigned short* __restrict__ O) {
    __shared__ __align__(16) unsigned char SMEM[SMEM_BYTES];
    attn_body(blockIdx.x, SMEM, Q, Kf, Vf, O);
}

// ---------------------------------------------------------------------------
extern "C" void kernel_launch(void* const* d_in, const int* in_sizes, int n_in,
                              void* d_out, int out_size, void* d_ws, size_t ws_size,
                              hipStream_t stream) {
    const float* x  = (const float*)d_in[0];
    const float* Wq = (const float*)d_in[1];
    const float* bq = (const float*)d_in[2];
    const float* Wk = (const float*)d_in[3];
    const float* bk = (const float*)d_in[4];
    const float* Wv = (const float*)d_in[5];
    const float* bv = (const float*)d_in[6];
    const float* Wo = (const float*)d_in[7];
    const float* bo = (const float*)d_in[8];
    float* out = (float*)d_out;
    unsigned short* ws = (unsigned short*)d_ws;

    const size_t WS_DATA = 4ull * 4194304ull * sizeof(unsigned short);  // 32 MB

    if (ws_size >= WS_DATA + 64) {
        // barrier counters live just past the 32 MB data region; the memset
        // is part of the captured graph, so every replay starts from zero.
        unsigned* bar = (unsigned*)((char*)d_ws + WS_DATA);
        hipMemsetAsync(bar, 0, 4 * sizeof(unsigned), stream);
        hipLaunchKernelGGL(mha_fused, dim3(512), dim3(256), 0, stream,
                           x, Wq, bq, Wk, bk, Wv, bv, Wo, bo, out, ws, bar);
    } else {
        // proven 5-kernel pipeline
        unsigned short* xb    = ws;
        unsigned short* q_ws  = xb + (size_t)MROWS * EMB;
        unsigned short* k_ws  = q_ws + (size_t)MROWS * EMB;
        unsigned short* vt_ws = k_ws + (size_t)MROWS * EMB;
        unsigned short* o_ws  = xb;
        unsigned short* wqkv  = (unsigned short*)d_out;
        unsigned short* wo_b  = q_ws;

        dim3 blk(256);
        cvt_all<<<dim3((MROWS * EMB + 3 * EMB * EMB) / 2048), blk, 0, stream>>>(
            x, Wq, Wk, Wv, xb, wqkv);
        gemm128<true, 128><<<dim3(768), blk, 0, stream>>>(
            xb, wqkv, wqkv + EMB * EMB, wqkv + 2 * EMB * EMB,
            bq, bk, bv, q_ws, k_ws, vt_ws);
        attn_fused<<<dim3(512), blk, 0, stream>>>(q_ws, k_ws, vt_ws, o_ws);
        cvt_bf16<<<dim3(EMB * EMB / 2048), blk, 0, stream>>>(Wo, wo_b, EMB * EMB);
        gemm128<false, 64><<<dim3(512), blk, 0, stream>>>(
            o_ws, wo_b, wo_b, wo_b, bo, bo, bo, d_out, d_out, d_out);
    }
}